// Round 1
// baseline (451.567 us; speedup 1.0000x reference)
//
#include <hip/hip_runtime.h>
#include <hip/hip_bf16.h>
#include <math.h>

#define BS   16
#define NQ   900
#define NCLS 1000
#define NT   100          // targets per batch (rows for LSA)
#define MQ   900          // queries (cols for LSA)
#define NCOL (BS * NT)    // 1600 total target columns

// ---------------------------------------------------------------------------
// Kernel 1: per-row softmax stats (max, sum of exp) over 1000 classes.
// One block (256 threads) per row; 14400 rows.
// ---------------------------------------------------------------------------
__global__ __launch_bounds__(256) void rowstats_kernel(
    const float* __restrict__ logits, float* __restrict__ stats) {
  const int row = blockIdx.x;
  const float* x = logits + (size_t)row * NCLS;
  const int tid = threadIdx.x;
  const int wave = tid >> 6, lane = tid & 63;

  float lmax = -INFINITY;
  for (int j = tid; j < NCLS; j += 256) lmax = fmaxf(lmax, x[j]);
  for (int o = 32; o > 0; o >>= 1) lmax = fmaxf(lmax, __shfl_xor(lmax, o, 64));
  __shared__ float wmax[4];
  if (lane == 0) wmax[wave] = lmax;
  __syncthreads();
  const float rmax = fmaxf(fmaxf(wmax[0], wmax[1]), fmaxf(wmax[2], wmax[3]));

  float psum = 0.f;
  for (int j = tid; j < NCLS; j += 256) psum += expf(x[j] - rmax);
  for (int o = 32; o > 0; o >>= 1) psum += __shfl_xor(psum, o, 64);
  __shared__ float wsum[4];
  if (lane == 0) wsum[wave] = psum;
  __syncthreads();
  if (tid == 0) {
    stats[2 * row]     = rmax;
    stats[2 * row + 1] = wsum[0] + wsum[1] + wsum[2] + wsum[3];
  }
}

// ---------------------------------------------------------------------------
// Kernel 2: cost matrix Cm[b,q,col] = L1(bbox) - softmax_prob[tgt_id].
// Also scatters the per-batch diagonal block (transposed) into costT for LSA:
// costT[b][r][q] = Cm[b][q][b*NT + r].
// One block per (b,q) row; 256 threads over 1600 cols.
// ---------------------------------------------------------------------------
__global__ __launch_bounds__(256) void cost_kernel(
    const float* __restrict__ logits, const float* __restrict__ boxes,
    const int* __restrict__ ids, const float* __restrict__ tbox,
    const float* __restrict__ stats, float* __restrict__ C,
    float* __restrict__ costT, int id_stride) {
  const int row = blockIdx.x;              // 0..14399
  const int b = row / NQ;
  const int q = row - b * NQ;
  const float4 bb = *reinterpret_cast<const float4*>(boxes + (size_t)row * 4);
  const float rmax = stats[2 * row];
  const float rsum = stats[2 * row + 1];
  const float* lrow = logits + (size_t)row * NCLS;
  float* crow = C + (size_t)row * NCOL;
  const int jlo = b * NT;

  for (int j = threadIdx.x; j < NCOL; j += 256) {
    const int id = ids[(size_t)j * id_stride];
    const float4 tb = *reinterpret_cast<const float4*>(tbox + (size_t)j * 4);
    float d = fabsf(bb.x - tb.x);
    d += fabsf(bb.y - tb.y);
    d += fabsf(bb.z - tb.z);
    d += fabsf(bb.w - tb.w);
    const float p = expf(lrow[id] - rmax) / rsum;
    const float cost = d + (-p);
    crow[j] = cost;
    const int r = j - jlo;
    if ((unsigned)r < (unsigned)NT) {
      costT[((size_t)b * NT + r) * MQ + q] = cost;
    }
  }
}

// ---------------------------------------------------------------------------
// Kernel 3: Jonker-Volgenant LSA, exact replica of the reference (float64
// potentials, first-index tie-break argmin). One block per batch element.
// cost[r][c], r in [0,100) targets, c in [0,900) queries.
// ---------------------------------------------------------------------------
__global__ __launch_bounds__(256) void lsa_kernel(
    const float* __restrict__ costT, float* __restrict__ out_i,
    float* __restrict__ out_j) {
  const int b = blockIdx.x;
  const float* cost = costT + (size_t)b * NT * MQ;
  const int tid = threadIdx.x;
  const double DINF = __builtin_inf();

  __shared__ double u[NT + 1];
  __shared__ double v[MQ + 1];
  __shared__ double minv[MQ + 1];
  __shared__ int way[MQ + 1];
  __shared__ int p[MQ + 1];
  __shared__ unsigned char used[MQ + 1];
  __shared__ double red_val[256];
  __shared__ int red_idx[256];
  __shared__ int s_j0;
  __shared__ double s_delta;
  __shared__ int cols[NT];

  for (int j = tid; j <= MQ; j += 256) { v[j] = 0.0; p[j] = 0; way[j] = 0; }
  for (int i = tid; i <= NT; i += 256) u[i] = 0.0;
  __syncthreads();

  for (int i = 1; i <= NT; ++i) {
    for (int j = tid; j <= MQ; j += 256) { minv[j] = DINF; used[j] = 0; }
    if (tid == 0) { p[0] = i; s_j0 = 0; }
    __syncthreads();

    while (true) {
      const int j0 = s_j0;
      if (tid == 0) used[j0] = 1;
      __syncthreads();
      const int i0 = p[j0];
      const double ui0 = u[i0];
      const float* crow = cost + (size_t)(i0 - 1) * MQ;

      // scan free columns: relax minv/way, track local (val, idx) min.
      double bestv = DINF;
      int bestj = 0x7fffffff;
      for (int j = tid + 1; j <= MQ; j += 256) {
        if (!used[j]) {
          const double cur = (double)crow[j - 1] - ui0 - v[j];
          double mv = minv[j];
          if (cur < mv) { mv = cur; minv[j] = cur; way[j] = j0; }
          if (mv < bestv) { bestv = mv; bestj = j; }
        }
      }
      red_val[tid] = bestv;
      red_idx[tid] = bestj;
      __syncthreads();
      for (int s = 128; s > 0; s >>= 1) {
        if (tid < s) {
          const double ov = red_val[tid + s];
          const int oj = red_idx[tid + s];
          if (ov < red_val[tid] ||
              (ov == red_val[tid] && oj < red_idx[tid])) {
            red_val[tid] = ov;
            red_idx[tid] = oj;
          }
        }
        __syncthreads();
      }
      if (tid == 0) { s_delta = red_val[0]; s_j0 = red_idx[0]; }
      __syncthreads();
      const double delta = s_delta;
      const int j1 = s_j0;
      // update potentials (used columns map to distinct rows -> no races)
      for (int j = tid; j <= MQ; j += 256) {
        if (used[j]) { u[p[j]] += delta; v[j] -= delta; }
        else          minv[j] -= delta;
      }
      __syncthreads();
      if (p[j1] == 0) break;
    }

    // augment along the alternating path (serial, thread 0)
    if (tid == 0) {
      int j0 = s_j0;
      while (j0 != 0) {
        const int j1 = way[j0];
        p[j0] = p[j1];
        j0 = j1;
      }
    }
    __syncthreads();
  }

  // extract assignment: cols[row] = column
  for (int j = tid + 1; j <= MQ; j += 256)
    if (p[j] > 0) cols[p[j] - 1] = j - 1;
  __syncthreads();

  // order = argsort(cols); idx_i = cols[order], idx_j = order
  for (int r = tid; r < NT; r += 256) {
    const int c = cols[r];
    int rank = 0;
    for (int r2 = 0; r2 < NT; ++r2) rank += (cols[r2] < c);
    out_i[b * NT + rank] = (float)c;
    out_j[b * NT + rank] = (float)r;
  }
}

extern "C" void kernel_launch(void* const* d_in, const int* in_sizes, int n_in,
                              void* d_out, int out_size, void* d_ws,
                              size_t ws_size, hipStream_t stream) {
  const float* logits = (const float*)d_in[0];
  const float* boxes  = (const float*)d_in[1];
  const int*   ids    = (const int*)d_in[2];
  const float* tbox   = (const float*)d_in[3];

  float* C     = (float*)d_out;                      // 16*900*1600
  float* out_i = C + (size_t)BS * NQ * NCOL;         // 1600
  float* out_j = out_i + NCOL;                       // 1600

  float* stats = (float*)d_ws;                       // 2 * 14400 floats
  float* costT = stats + 2 * BS * NQ;                // 16*100*900 floats

  // tgt_ids is int64 in the reference; detect whether the harness passed
  // it as int32 (element count 1600) or raw int64 words (3200).
  const int id_stride = (in_sizes[2] == 2 * NCOL) ? 2 : 1;

  rowstats_kernel<<<BS * NQ, 256, 0, stream>>>(logits, stats);
  cost_kernel<<<BS * NQ, 256, 0, stream>>>(logits, boxes, ids, tbox, stats, C,
                                           costT, id_stride);
  lsa_kernel<<<BS, 256, 0, stream>>>(costT, out_i, out_j);
}

// Round 2
// 375.662 us; speedup vs baseline: 1.2021x; 1.2021x over previous
//
#include <hip/hip_runtime.h>
#include <hip/hip_bf16.h>
#include <math.h>

#define BS   16
#define NQ   900
#define NCLS 1000
#define NT   100          // targets per batch (rows for LSA)
#define MQ   900          // queries (cols for LSA)
#define NCOL (BS * NT)    // 1600 total target columns
#define NSLOT 15          // ceil(MQ / 64)

// ---------------------------------------------------------------------------
// Kernel 1: per-row softmax stats (max, sum of exp) over 1000 classes.
// ---------------------------------------------------------------------------
__global__ __launch_bounds__(256) void rowstats_kernel(
    const float* __restrict__ logits, float* __restrict__ stats) {
  const int row = blockIdx.x;
  const float* x = logits + (size_t)row * NCLS;
  const int tid = threadIdx.x;
  const int wave = tid >> 6, lane = tid & 63;

  float lmax = -INFINITY;
  for (int j = tid; j < NCLS; j += 256) lmax = fmaxf(lmax, x[j]);
  for (int o = 32; o > 0; o >>= 1) lmax = fmaxf(lmax, __shfl_xor(lmax, o, 64));
  __shared__ float wmax[4];
  if (lane == 0) wmax[wave] = lmax;
  __syncthreads();
  const float rmax = fmaxf(fmaxf(wmax[0], wmax[1]), fmaxf(wmax[2], wmax[3]));

  float psum = 0.f;
  for (int j = tid; j < NCLS; j += 256) psum += expf(x[j] - rmax);
  for (int o = 32; o > 0; o >>= 1) psum += __shfl_xor(psum, o, 64);
  __shared__ float wsum[4];
  if (lane == 0) wsum[wave] = psum;
  __syncthreads();
  if (tid == 0) {
    stats[2 * row]     = rmax;
    stats[2 * row + 1] = wsum[0] + wsum[1] + wsum[2] + wsum[3];
  }
}

// ---------------------------------------------------------------------------
// Kernel 2: cost matrix Cm[b,q,col] = L1(bbox) - softmax_prob[tgt_id].
// Also scatters the per-batch diagonal block (transposed) into costT.
// ---------------------------------------------------------------------------
__global__ __launch_bounds__(256) void cost_kernel(
    const float* __restrict__ logits, const float* __restrict__ boxes,
    const int* __restrict__ ids, const float* __restrict__ tbox,
    const float* __restrict__ stats, float* __restrict__ C,
    float* __restrict__ costT, int id_stride) {
  const int row = blockIdx.x;              // 0..14399
  const int b = row / NQ;
  const int q = row - b * NQ;
  const float4 bb = *reinterpret_cast<const float4*>(boxes + (size_t)row * 4);
  const float rmax = stats[2 * row];
  const float rsum = stats[2 * row + 1];
  const float* lrow = logits + (size_t)row * NCLS;
  float* crow = C + (size_t)row * NCOL;
  const int jlo = b * NT;

  for (int j = threadIdx.x; j < NCOL; j += 256) {
    const int id = ids[(size_t)j * id_stride];
    const float4 tb = *reinterpret_cast<const float4*>(tbox + (size_t)j * 4);
    float d = fabsf(bb.x - tb.x);
    d += fabsf(bb.y - tb.y);
    d += fabsf(bb.z - tb.z);
    d += fabsf(bb.w - tb.w);
    const float p = expf(lrow[id] - rmax) / rsum;
    const float cost = d + (-p);
    crow[j] = cost;
    const int r = j - jlo;
    if ((unsigned)r < (unsigned)NT) {
      costT[((size_t)b * NT + r) * MQ + q] = cost;
    }
  }
}

// ---------------------------------------------------------------------------
// Kernel 3: Jonker-Volgenant LSA, exact replica of the reference recursion
// (float64 potentials, first-index tie-break). ONE WAVE per batch element.
// Columns are lane-strided: real col c (0-based) lives in slot c>>6 of lane
// c&63. v / minv / used are register-resident; u / p / way stay in LDS.
// ---------------------------------------------------------------------------
__global__ __launch_bounds__(64) void lsa_kernel(
    const float* __restrict__ costT, float* __restrict__ out_i,
    float* __restrict__ out_j) {
  const int b = blockIdx.x;
  const float* cost = costT + (size_t)b * NT * MQ;
  const int lane = threadIdx.x;
  const double DINF = __builtin_inf();

  __shared__ double u[NT + 1];
  __shared__ int p[MQ + 1];
  __shared__ int way[MQ + 1];
  __shared__ int cols[NT];

  double v[NSLOT], minv[NSLOT];
  float cf[NSLOT], cfn[NSLOT];

#pragma unroll
  for (int s = 0; s < NSLOT; ++s) v[s] = 0.0;
  for (int j = lane; j <= MQ; j += 64) p[j] = 0;
  for (int i = lane; i <= NT; i += 64) u[i] = 0.0;
  __syncthreads();

  for (int i = 1; i <= NT; ++i) {
#pragma unroll
    for (int s = 0; s < NSLOT; ++s) minv[s] = DINF;
    unsigned usedm = 0;
    if (lane == 0) p[0] = i;
    __syncthreads();

    int j0 = 0;
    int i0 = i;                 // p[0] == i
    double ui0 = u[i0];
    {
      const float* crow = cost + (size_t)(i0 - 1) * MQ;
#pragma unroll
      for (int s = 0; s < NSLOT; ++s) {
        const int c = s * 64 + lane;
        cf[s] = (c < MQ) ? crow[c] : 0.f;
      }
    }

    while (true) {
      // mark used[j0] (j0 == 0 is the virtual column, handled via lane 0)
      if (j0 > 0 && lane == ((j0 - 1) & 63))
        usedm |= 1u << ((j0 - 1) >> 6);

      // scan free columns: relax minv/way, local lexicographic min
      double bestv = DINF;
      int bestj = 0x7fffffff;
#pragma unroll
      for (int s = 0; s < NSLOT; ++s) {
        const int c = s * 64 + lane;
        if (c < MQ && !((usedm >> s) & 1u)) {
          const double cur = (double)cf[s] - ui0 - v[s];
          if (cur < minv[s]) { minv[s] = cur; way[c + 1] = j0; }
          if (minv[s] < bestv) { bestv = minv[s]; bestj = c + 1; }
        }
      }
      // wave argmin, first-index tie-break
      for (int o = 32; o > 0; o >>= 1) {
        const double ov = __shfl_xor(bestv, o, 64);
        const int    oj = __shfl_xor(bestj, o, 64);
        if (ov < bestv || (ov == bestv && oj < bestj)) { bestv = ov; bestj = oj; }
      }
      const double delta = bestv;
      const int j1 = bestj;
      const int pj1 = p[j1];

      // prefetch next pivot row while we update potentials
      if (pj1 != 0) {
        const float* crow = cost + (size_t)(pj1 - 1) * MQ;
#pragma unroll
        for (int s = 0; s < NSLOT; ++s) {
          const int c = s * 64 + lane;
          cfn[s] = (c < MQ) ? crow[c] : 0.f;
        }
      }

      // potential updates (used cols -> distinct rows: race-free u updates)
#pragma unroll
      for (int s = 0; s < NSLOT; ++s) {
        const int c = s * 64 + lane;
        if (c < MQ) {
          if ((usedm >> s) & 1u) {
            v[s] -= delta;
            u[p[c + 1]] += delta;
          } else {
            minv[s] -= delta;
          }
        }
      }
      if (lane == 0) u[i] += delta;   // virtual column 0: p[0] == i
      __syncthreads();

      j0 = j1;
      if (pj1 == 0) break;
      i0 = pj1;
      ui0 = u[i0];
#pragma unroll
      for (int s = 0; s < NSLOT; ++s) cf[s] = cfn[s];
    }

    // augment along the alternating path (serial, lane 0)
    if (lane == 0) {
      int ja = j0;
      while (ja != 0) { const int jb = way[ja]; p[ja] = p[jb]; ja = jb; }
    }
    __syncthreads();
  }

  // extract assignment: cols[row] = column
  for (int j = lane + 1; j <= MQ; j += 64)
    if (p[j] > 0) cols[p[j] - 1] = j - 1;
  __syncthreads();

  // order = argsort(cols); idx_i = cols[order], idx_j = order
  for (int r = lane; r < NT; r += 64) {
    const int c = cols[r];
    int rank = 0;
    for (int r2 = 0; r2 < NT; ++r2) rank += (cols[r2] < c);
    out_i[b * NT + rank] = (float)c;
    out_j[b * NT + rank] = (float)r;
  }
}

extern "C" void kernel_launch(void* const* d_in, const int* in_sizes, int n_in,
                              void* d_out, int out_size, void* d_ws,
                              size_t ws_size, hipStream_t stream) {
  const float* logits = (const float*)d_in[0];
  const float* boxes  = (const float*)d_in[1];
  const int*   ids    = (const int*)d_in[2];
  const float* tbox   = (const float*)d_in[3];

  float* C     = (float*)d_out;                      // 16*900*1600
  float* out_i = C + (size_t)BS * NQ * NCOL;         // 1600
  float* out_j = out_i + NCOL;                       // 1600

  float* stats = (float*)d_ws;                       // 2 * 14400 floats
  float* costT = stats + 2 * BS * NQ;                // 16*100*900 floats

  const int id_stride = (in_sizes[2] == 2 * NCOL) ? 2 : 1;

  rowstats_kernel<<<BS * NQ, 256, 0, stream>>>(logits, stats);
  cost_kernel<<<BS * NQ, 256, 0, stream>>>(logits, boxes, ids, tbox, stats, C,
                                           costT, id_stride);
  lsa_kernel<<<BS, 64, 0, stream>>>(costT, out_i, out_j);
}